// Round 1
// baseline (144.619 us; speedup 1.0000x reference)
//
#include <hip/hip_runtime.h>

#define NBINS 10
#define PAD   11          // pad 10 -> 11: dword stride 22, gcd(22,32)=2 -> optimal b64 banking
#define BLOCK 256
#define GRID  2048

// ws layout: double gsum[10] ; unsigned gcnt[10]
__global__ void ghm_init(double* gsum, unsigned* gcnt) {
    int t = threadIdx.x;
    if (t < NBINS) { gsum[t] = 0.0; gcnt[t] = 0u; }
}

__global__ __launch_bounds__(BLOCK) void ghm_main(const float4* __restrict__ pred,
                                                  const float4* __restrict__ targ,
                                                  int n4,
                                                  double* __restrict__ gsum,
                                                  unsigned* __restrict__ gcnt) {
    __shared__ float2 hist[BLOCK][PAD];
    const int tid = threadIdx.x;

    // private histogram rows: no sync needed, each thread owns its row
#pragma unroll
    for (int b = 0; b < NBINS; ++b) hist[tid][b] = make_float2(0.0f, 0.0f);

    int i = blockIdx.x * BLOCK + tid;
    const int stride = GRID * BLOCK;

    for (; i < n4; i += stride) {
        float4 p = pred[i];
        float4 t = targ[i];

#define ELEM(px, tx)                                                         \
        {                                                                    \
            float x  = (px);                                                 \
            float tt = (tx);                                                 \
            float ax = fabsf(x);                                             \
            float e  = __expf(-ax);          /* exp(-|x|) in (0,1] */        \
            float r  = __builtin_amdgcn_rcpf(1.0f + e);                      \
            float sg = (x >= 0.0f ? 1.0f : e) * r;   /* sigmoid(x) */        \
            float g  = fabsf(sg - tt);                                       \
            int   b  = (int)(g * 10.0f);                                     \
            b = b > 9 ? 9 : b;                                               \
            float l   = __logf(1.0f + e);    /* log1p(exp(-|x|)) */          \
            float bce = fmaxf(x, 0.0f) - x * tt + l;                         \
            float2 h = hist[tid][b];                                         \
            h.x += bce;                                                      \
            h.y += 1.0f;                                                     \
            hist[tid][b] = h;                                                \
        }

        ELEM(p.x, t.x)
        ELEM(p.y, t.y)
        ELEM(p.z, t.z)
        ELEM(p.w, t.w)
#undef ELEM
    }

    __syncthreads();

    // tree-reduce the 256 private rows
    for (int off = BLOCK / 2; off > 0; off >>= 1) {
        if (tid < off) {
#pragma unroll
            for (int b = 0; b < NBINS; ++b) {
                float2 a = hist[tid][b];
                float2 c = hist[tid + off][b];
                a.x += c.x;
                a.y += c.y;
                hist[tid][b] = a;
            }
        }
        __syncthreads();
    }

    if (tid < NBINS) {
        atomicAdd(&gsum[tid], (double)hist[0][tid].x);
        atomicAdd(&gcnt[tid], (unsigned)hist[0][tid].y);  // block count <= 32768, exact in f32
    }
}

__global__ void ghm_finalize(const double* __restrict__ gsum,
                             const unsigned* __restrict__ gcnt,
                             float* __restrict__ out) {
    if (threadIdx.x == 0 && blockIdx.x == 0) {
        double acc = 0.0;
        int n = 0;
        for (int b = 0; b < NBINS; ++b) {
            unsigned c = gcnt[b];
            if (c > 0u) {
                ++n;
                acc += gsum[b] / (double)c;
            }
        }
        if (n < 1) n = 1;
        out[0] = (float)(acc / (double)n);
    }
}

extern "C" void kernel_launch(void* const* d_in, const int* in_sizes, int n_in,
                              void* d_out, int out_size, void* d_ws, size_t ws_size,
                              hipStream_t stream) {
    const float4* pred = (const float4*)d_in[0];
    const float4* targ = (const float4*)d_in[1];
    double*   gsum = (double*)d_ws;
    unsigned* gcnt = (unsigned*)((char*)d_ws + NBINS * sizeof(double));
    float* out = (float*)d_out;

    int n4 = in_sizes[0] / 4;

    ghm_init<<<1, 64, 0, stream>>>(gsum, gcnt);
    ghm_main<<<GRID, BLOCK, 0, stream>>>(pred, targ, n4, gsum, gcnt);
    ghm_finalize<<<1, 64, 0, stream>>>(gsum, gcnt, out);
}

// Round 2
// 134.384 us; speedup vs baseline: 1.0762x; 1.0762x over previous
//
#include <hip/hip_runtime.h>

#define NBINS 10
#define BLOCK 256
#define GRID  2048
#define NWAVE (BLOCK / 64)

// ws layout: double gsum[10] ; unsigned gcnt[10]
__global__ void ghm_init(double* gsum, unsigned* gcnt) {
    int t = threadIdx.x;
    if (t < NBINS) { gsum[t] = 0.0; gcnt[t] = 0u; }
}

__global__ __launch_bounds__(BLOCK) void ghm_main(const float4* __restrict__ pred,
                                                  const float4* __restrict__ targ,
                                                  int n4,
                                                  double* __restrict__ gsum,
                                                  unsigned* __restrict__ gcnt) {
    // Register-resident histogram: 10 bins x {bce_sum, count}, all indices
    // compile-time constant (runtime-indexed arrays would go to scratch).
    float asum[NBINS];
    float acnt[NBINS];
#pragma unroll
    for (int b = 0; b < NBINS; ++b) { asum[b] = 0.0f; acnt[b] = 0.0f; }

    int i = blockIdx.x * BLOCK + threadIdx.x;
    const int stride = GRID * BLOCK;

    for (; i < n4; i += stride) {
        float4 p = pred[i];
        float4 t = targ[i];

#define ELEM(px, tx)                                                         \
        {                                                                    \
            float x  = (px);                                                 \
            float tt = (tx);                                                 \
            float ax = fabsf(x);                                             \
            float e  = __expf(-ax);          /* exp(-|x|) in (0,1] */        \
            float r  = __builtin_amdgcn_rcpf(1.0f + e);                      \
            float sg = (x >= 0.0f ? 1.0f : e) * r;   /* sigmoid(x) */        \
            float g  = fabsf(sg - tt);                                       \
            int   bin = (int)(g * 10.0f);                                    \
            bin = bin > 9 ? 9 : bin;                                         \
            float bce = fmaxf(x, 0.0f) - x * tt + __logf(1.0f + e);          \
            _Pragma("unroll")                                                \
            for (int b = 0; b < NBINS; ++b) {                                \
                float m = (bin == b) ? 1.0f : 0.0f;                          \
                asum[b] = fmaf(m, bce, asum[b]);                             \
                acnt[b] += m;                                                \
            }                                                                \
        }

        ELEM(p.x, t.x)
        ELEM(p.y, t.y)
        ELEM(p.z, t.z)
        ELEM(p.w, t.w)
#undef ELEM
    }

    // Wave-level butterfly reduction (64 lanes), once per kernel.
#pragma unroll
    for (int b = 0; b < NBINS; ++b) {
#pragma unroll
        for (int m = 1; m < 64; m <<= 1) {
            asum[b] += __shfl_xor(asum[b], m, 64);
            acnt[b] += __shfl_xor(acnt[b], m, 64);
        }
    }

    __shared__ float2 wred[NWAVE][NBINS];
    const int wid  = threadIdx.x >> 6;
    const int lane = threadIdx.x & 63;
    if (lane == 0) {
#pragma unroll
        for (int b = 0; b < NBINS; ++b)
            wred[wid][b] = make_float2(asum[b], acnt[b]);
    }
    __syncthreads();

    if (threadIdx.x < NBINS) {
        float s = 0.0f, c = 0.0f;
#pragma unroll
        for (int w = 0; w < NWAVE; ++w) {
            s += wred[w][threadIdx.x].x;
            c += wred[w][threadIdx.x].y;
        }
        atomicAdd(&gsum[threadIdx.x], (double)s);
        atomicAdd(&gcnt[threadIdx.x], (unsigned)c);  // block count <= 32768, exact in f32
    }
}

__global__ void ghm_finalize(const double* __restrict__ gsum,
                             const unsigned* __restrict__ gcnt,
                             float* __restrict__ out) {
    if (threadIdx.x == 0 && blockIdx.x == 0) {
        double acc = 0.0;
        int n = 0;
        for (int b = 0; b < NBINS; ++b) {
            unsigned c = gcnt[b];
            if (c > 0u) {
                ++n;
                acc += gsum[b] / (double)c;
            }
        }
        if (n < 1) n = 1;
        out[0] = (float)(acc / (double)n);
    }
}

extern "C" void kernel_launch(void* const* d_in, const int* in_sizes, int n_in,
                              void* d_out, int out_size, void* d_ws, size_t ws_size,
                              hipStream_t stream) {
    const float4* pred = (const float4*)d_in[0];
    const float4* targ = (const float4*)d_in[1];
    double*   gsum = (double*)d_ws;
    unsigned* gcnt = (unsigned*)((char*)d_ws + NBINS * sizeof(double));
    float* out = (float*)d_out;

    int n4 = in_sizes[0] / 4;

    ghm_init<<<1, 64, 0, stream>>>(gsum, gcnt);
    ghm_main<<<GRID, BLOCK, 0, stream>>>(pred, targ, n4, gsum, gcnt);
    ghm_finalize<<<1, 64, 0, stream>>>(gsum, gcnt, out);
}